// Round 7
// baseline (42.714 us; speedup 1.0000x reference)
//
#include <hip/hip_runtime.h>
#include <hip/hip_bf16.h>
#include <math.h>

#define BB 64
#define CC 3
#define HH 384
#define WW 384
#define HW (HH * WW)

// Each block: 64x24 output tile of one image (3 channels), staged via LDS.
// 512 threads = 64(x) x 8(y); each thread does 3 rows (stride 8).
#define TILE_W 64
#define TILE_H 24
#define TX_TILES (WW / TILE_W)                 // 6
#define TY_TILES (HH / TILE_H)                 // 16
#define TILES_PER_IMG (TX_TILES * TY_TILES)    // 96
#define NBLOCKS (BB * TILES_PER_IMG)           // 6144 (divisible by 8)

// Rotated bbox of 64x24 at <=15deg: LW <= 71, LH <= 43.
#define LW_STRIDE 71
#define LH_MAX 43
// LDS = 43*71 float4 = 48848 B -> 3 blocks/CU x 8 waves = 24 waves (75%)

__global__ __launch_bounds__(512, 6) void GeometricAugment_kernel(
    const float* __restrict__ x,
    const float* __restrict__ angles,
    const float* __restrict__ dx,
    const float* __restrict__ dy,
    float* __restrict__ out) {

    __shared__ float4 lds4[LH_MAX * LW_STRIDE];

    // XCD-chunked bijective swizzle (6144 % 8 == 0)
    int bid = blockIdx.x;
    int swz = (bid & 7) * (NBLOCKS / 8) + (bid >> 3);

    int b   = swz / TILES_PER_IMG;
    int t   = swz - b * TILES_PER_IMG;
    int tyb = t / TX_TILES;
    int txb = t - tyb * TX_TILES;

    int tid = threadIdx.x;
    int tx  = tid & 63;   // 0..63
    int tyl = tid >> 6;   // 0..7

    const int X0 = txb * TILE_W;
    const int Y0 = tyb * TILE_H;

    const float cx = (WW - 1) * 0.5f;
    const float cy = (HH - 1) * 0.5f;

    float rad = angles[b] * (float)(M_PI / 180.0);
    float si, co;
    __sincosf(rad, &si, &co);
    float txs = dx[b];
    float tys = dy[b];

    // tile-corner sample coords (uniform across block)
    float xo0 = (float)X0 - cx - txs;
    float xo1 = (float)(X0 + TILE_W - 1) - cx - txs;
    float yo0 = (float)Y0 - cy - tys;
    float yo1 = (float)(Y0 + TILE_H - 1) - cy - tys;

    float xsA = co * xo0 + si * yo0 + cx;
    float xsB = co * xo1 + si * yo0 + cx;
    float xsC = co * xo0 + si * yo1 + cx;
    float xsD = co * xo1 + si * yo1 + cx;
    float ysA = -si * xo0 + co * yo0 + cy;
    float ysB = -si * xo1 + co * yo0 + cy;
    float ysC = -si * xo0 + co * yo1 + cy;
    float ysD = -si * xo1 + co * yo1 + cy;

    float xsmin = fminf(fminf(xsA, xsB), fminf(xsC, xsD));
    float xsmax = fmaxf(fmaxf(xsA, xsB), fmaxf(xsC, xsD));
    float ysmin = fminf(fminf(ysA, ysB), fminf(ysC, ysD));
    float ysmax = fmaxf(fmaxf(ysA, ysB), fmaxf(ysC, ysD));

    int ximin = (int)floorf(xsmin) - 1;
    int yimin = (int)floorf(ysmin) - 1;
    int LH = (int)floorf(ysmax) + 2 - yimin + 1;  // <= 43
    LH = min(LH, LH_MAX);

    // block-uniform interior test (full staged window in-bounds)
    bool interior = (ximin >= 0) && (yimin >= 0) &&
                    (ximin + LW_STRIDE <= WW) && (yimin + LH <= HH);

    const float* imgb = x + (size_t)b * CC * HW;

    int nelem = LH * LW_STRIDE;
    if (interior) {
        // ---- fast staging: no clamps ----
        const float* srcb = imgb + yimin * WW + ximin;
        for (int i = tid; i < nelem; i += 512) {
            int y  = i / LW_STRIDE;
            int xL = i - y * LW_STRIDE;
            const float* src = srcb + y * WW + xL;
            lds4[i] = make_float4(src[0], src[HW], src[2 * HW], 0.0f);
        }
    } else {
        // ---- clamped staging ----
        for (int i = tid; i < nelem; i += 512) {
            int y  = i / LW_STRIDE;
            int xL = i - y * LW_STRIDE;
            int gy = min(max(yimin + y, 0), HH - 1);
            int gx = min(max(ximin + xL, 0), WW - 1);
            const float* src = imgb + gy * WW + gx;
            lds4[i] = make_float4(src[0], src[HW], src[2 * HW], 0.0f);
        }
    }
    __syncthreads();

    // ---- gather from LDS ----
    int x_out = X0 + tx;
    float xo = (float)x_out - cx - txs;
    float yo = (float)(Y0 + tyl) - cy - tys;

    float xs =  co * xo + si * yo + cx;
    float ys = -si * xo + co * yo + cy;
    const float dxs = 8.0f * si;
    const float dys = 8.0f * co;

    float* outb = out + (size_t)b * CC * HW + (size_t)Y0 * WW + x_out;

    if (interior) {
        #pragma unroll
        for (int r = 0; r < TILE_H / 8; ++r) {
            float x0f = floorf(xs);
            float y0f = floorf(ys);
            float wx = xs - x0f;
            float wy = ys - y0f;
            int base = ((int)y0f - yimin) * LW_STRIDE + ((int)x0f - ximin);

            float4 q00 = lds4[base];
            float4 q01 = lds4[base + 1];
            float4 q10 = lds4[base + LW_STRIDE];
            float4 q11 = lds4[base + LW_STRIDE + 1];

            float* o = outb + (size_t)(tyl + r * 8) * WW;
            {
                float top = q00.x + wx * (q01.x - q00.x);
                float bot = q10.x + wx * (q11.x - q10.x);
                float v = top + wy * (bot - top);
                __builtin_nontemporal_store(fminf(fmaxf(v, 0.0f), 1.0f), o);
            }
            {
                float top = q00.y + wx * (q01.y - q00.y);
                float bot = q10.y + wx * (q11.y - q10.y);
                float v = top + wy * (bot - top);
                __builtin_nontemporal_store(fminf(fmaxf(v, 0.0f), 1.0f), o + HW);
            }
            {
                float top = q00.z + wx * (q01.z - q00.z);
                float bot = q10.z + wx * (q11.z - q10.z);
                float v = top + wy * (bot - top);
                __builtin_nontemporal_store(fminf(fmaxf(v, 0.0f), 1.0f), o + 2 * HW);
            }
            xs += dxs;
            ys += dys;
        }
    } else {
        #pragma unroll
        for (int r = 0; r < TILE_H / 8; ++r) {
            float x0f = floorf(xs);
            float y0f = floorf(ys);
            float wx = xs - x0f;
            float wy = ys - y0f;
            int x0 = (int)x0f;
            int y0 = (int)y0f;
            int x1 = x0 + 1;
            int y1 = y0 + 1;

            float vx0 = (x0 >= 0 && x0 < WW) ? 1.0f : 0.0f;
            float vx1 = (x1 >= 0 && x1 < WW) ? 1.0f : 0.0f;
            float vy0 = (y0 >= 0 && y0 < HH) ? 1.0f : 0.0f;
            float vy1 = (y1 >= 0 && y1 < HH) ? 1.0f : 0.0f;

            float w00 = (1.0f - wx) * (1.0f - wy) * vx0 * vy0;
            float w01 = wx * (1.0f - wy) * vx1 * vy0;
            float w10 = (1.0f - wx) * wy * vx0 * vy1;
            float w11 = wx * wy * vx1 * vy1;

            int base = (y0 - yimin) * LW_STRIDE + (x0 - ximin);

            float4 q00 = lds4[base];
            float4 q01 = lds4[base + 1];
            float4 q10 = lds4[base + LW_STRIDE];
            float4 q11 = lds4[base + LW_STRIDE + 1];

            float* o = outb + (size_t)(tyl + r * 8) * WW;
            {
                float v = q00.x * w00 + q01.x * w01 + q10.x * w10 + q11.x * w11;
                __builtin_nontemporal_store(fminf(fmaxf(v, 0.0f), 1.0f), o);
            }
            {
                float v = q00.y * w00 + q01.y * w01 + q10.y * w10 + q11.y * w11;
                __builtin_nontemporal_store(fminf(fmaxf(v, 0.0f), 1.0f), o + HW);
            }
            {
                float v = q00.z * w00 + q01.z * w01 + q10.z * w10 + q11.z * w11;
                __builtin_nontemporal_store(fminf(fmaxf(v, 0.0f), 1.0f), o + 2 * HW);
            }
            xs += dxs;
            ys += dys;
        }
    }
}

extern "C" void kernel_launch(void* const* d_in, const int* in_sizes, int n_in,
                              void* d_out, int out_size, void* d_ws, size_t ws_size,
                              hipStream_t stream) {
    const float* x      = (const float*)d_in[0];
    const float* angles = (const float*)d_in[1];
    const float* dx     = (const float*)d_in[2];
    const float* dy     = (const float*)d_in[3];
    float* out = (float*)d_out;

    GeometricAugment_kernel<<<NBLOCKS, 512, 0, stream>>>(x, angles, dx, dy, out);
}

// Round 8
// 41.349 us; speedup vs baseline: 1.0330x; 1.0330x over previous
//
#include <hip/hip_runtime.h>
#include <hip/hip_bf16.h>
#include <math.h>

#define BB 64
#define CC 3
#define HH 384
#define WW 384
#define HW (HH * WW)

// Each block: 64x24 output tile of one image (3 channels), staged via LDS.
// 512 threads = 64(x) x 8(y); each thread does 3 rows (stride 8).
#define TILE_W 64
#define TILE_H 24
#define TX_TILES (WW / TILE_W)                 // 6
#define TY_TILES (HH / TILE_H)                 // 16
#define TILES_PER_IMG (TX_TILES * TY_TILES)    // 96
#define NBLOCKS (BB * TILES_PER_IMG)           // 6144 (divisible by 8)

// Rotated bbox of 64x24 at <=15deg: LW <= 71, LH <= 43.
// Channel-interleaved LDS [y][x][c]: x-stride 3 dwords (gcd(3,32)=1 ->
// 64 lanes cover 32 banks exactly 2x = free), row stride 213 (213%32=21).
// Corner pairs are 3 dwords apart -> ds_read2_b32 merging (offsets {0,3},{213,216}).
#define LW_STRIDE 71
#define LH_MAX 43
#define CSTR 3
#define ROWSTR (LW_STRIDE * CSTR)   // 213
// LDS = 43*213*4 = 36636 B -> 4 blocks/CU x 8 waves = 32 waves (100%)

__global__ __launch_bounds__(512, 8) void GeometricAugment_kernel(
    const float* __restrict__ x,
    const float* __restrict__ angles,
    const float* __restrict__ dx,
    const float* __restrict__ dy,
    float* __restrict__ out) {

    __shared__ float lds[LH_MAX * ROWSTR];

    // XCD-chunked bijective swizzle (6144 % 8 == 0)
    int bid = blockIdx.x;
    int swz = (bid & 7) * (NBLOCKS / 8) + (bid >> 3);

    int b   = swz / TILES_PER_IMG;
    int t   = swz - b * TILES_PER_IMG;
    int tyb = t / TX_TILES;
    int txb = t - tyb * TX_TILES;

    int tid = threadIdx.x;
    int tx  = tid & 63;   // 0..63
    int tyl = tid >> 6;   // 0..7

    const int X0 = txb * TILE_W;
    const int Y0 = tyb * TILE_H;

    const float cx = (WW - 1) * 0.5f;
    const float cy = (HH - 1) * 0.5f;

    float rad = angles[b] * (float)(M_PI / 180.0);
    float si, co;
    __sincosf(rad, &si, &co);
    float txs = dx[b];
    float tys = dy[b];

    // tile-corner sample coords (uniform across block)
    float xo0 = (float)X0 - cx - txs;
    float xo1 = (float)(X0 + TILE_W - 1) - cx - txs;
    float yo0 = (float)Y0 - cy - tys;
    float yo1 = (float)(Y0 + TILE_H - 1) - cy - tys;

    float xsA = co * xo0 + si * yo0 + cx;
    float xsB = co * xo1 + si * yo0 + cx;
    float xsC = co * xo0 + si * yo1 + cx;
    float xsD = co * xo1 + si * yo1 + cx;
    float ysA = -si * xo0 + co * yo0 + cy;
    float ysB = -si * xo1 + co * yo0 + cy;
    float ysC = -si * xo0 + co * yo1 + cy;
    float ysD = -si * xo1 + co * yo1 + cy;

    float xsmin = fminf(fminf(xsA, xsB), fminf(xsC, xsD));
    float xsmax = fmaxf(fmaxf(xsA, xsB), fmaxf(xsC, xsD));
    float ysmin = fminf(fminf(ysA, ysB), fminf(ysC, ysD));
    float ysmax = fmaxf(fmaxf(ysA, ysB), fmaxf(ysC, ysD));

    int ximin = (int)floorf(xsmin) - 1;
    int yimin = (int)floorf(ysmin) - 1;
    int LH = (int)floorf(ysmax) + 2 - yimin + 1;  // <= 43
    LH = min(LH, LH_MAX);

    // block-uniform interior test (full staged window in-bounds)
    bool interior = (ximin >= 0) && (yimin >= 0) &&
                    (ximin + LW_STRIDE <= WW) && (yimin + LH <= HH);

    const float* imgb = x + (size_t)b * CC * HW;

    int nelem = LH * LW_STRIDE;
    if (interior) {
        // ---- fast staging: no clamps ----
        const float* srcb = imgb + yimin * WW + ximin;
        for (int i = tid; i < nelem; i += 512) {
            int y  = i / LW_STRIDE;
            int xL = i - y * LW_STRIDE;
            const float* src = srcb + y * WW + xL;
            int a = y * ROWSTR + xL * CSTR;
            lds[a]     = src[0];
            lds[a + 1] = src[HW];
            lds[a + 2] = src[2 * HW];
        }
    } else {
        // ---- clamped staging ----
        for (int i = tid; i < nelem; i += 512) {
            int y  = i / LW_STRIDE;
            int xL = i - y * LW_STRIDE;
            int gy = min(max(yimin + y, 0), HH - 1);
            int gx = min(max(ximin + xL, 0), WW - 1);
            const float* src = imgb + gy * WW + gx;
            int a = y * ROWSTR + xL * CSTR;
            lds[a]     = src[0];
            lds[a + 1] = src[HW];
            lds[a + 2] = src[2 * HW];
        }
    }
    __syncthreads();

    // ---- gather from LDS ----
    int x_out = X0 + tx;
    float xo = (float)x_out - cx - txs;
    float yo = (float)(Y0 + tyl) - cy - tys;

    float xs =  co * xo + si * yo + cx;
    float ys = -si * xo + co * yo + cy;
    const float dxs = 8.0f * si;
    const float dys = 8.0f * co;

    float* outb = out + (size_t)b * CC * HW + (size_t)Y0 * WW + x_out;

    if (interior) {
        #pragma unroll
        for (int r = 0; r < TILE_H / 8; ++r) {
            float x0f = floorf(xs);
            float y0f = floorf(ys);
            float wx = xs - x0f;
            float wy = ys - y0f;
            int base = ((int)y0f - yimin) * ROWSTR + ((int)x0f - ximin) * CSTR;
            const float* l = lds + base;

            float* o = outb + (size_t)(tyl + r * 8) * WW;
            #pragma unroll
            for (int c = 0; c < CC; ++c) {
                float v00 = l[c];
                float v01 = l[c + CSTR];
                float v10 = l[c + ROWSTR];
                float v11 = l[c + ROWSTR + CSTR];
                float top = v00 + wx * (v01 - v00);
                float bot = v10 + wx * (v11 - v10);
                float v = top + wy * (bot - top);
                v = fminf(fmaxf(v, 0.0f), 1.0f);
                __builtin_nontemporal_store(v, o + (size_t)c * HW);
            }
            xs += dxs;
            ys += dys;
        }
    } else {
        #pragma unroll
        for (int r = 0; r < TILE_H / 8; ++r) {
            float x0f = floorf(xs);
            float y0f = floorf(ys);
            float wx = xs - x0f;
            float wy = ys - y0f;
            int x0 = (int)x0f;
            int y0 = (int)y0f;
            int x1 = x0 + 1;
            int y1 = y0 + 1;

            float vx0 = (x0 >= 0 && x0 < WW) ? 1.0f : 0.0f;
            float vx1 = (x1 >= 0 && x1 < WW) ? 1.0f : 0.0f;
            float vy0 = (y0 >= 0 && y0 < HH) ? 1.0f : 0.0f;
            float vy1 = (y1 >= 0 && y1 < HH) ? 1.0f : 0.0f;

            float w00 = (1.0f - wx) * (1.0f - wy) * vx0 * vy0;
            float w01 = wx * (1.0f - wy) * vx1 * vy0;
            float w10 = (1.0f - wx) * wy * vx0 * vy1;
            float w11 = wx * wy * vx1 * vy1;

            int base = (y0 - yimin) * ROWSTR + (x0 - ximin) * CSTR;
            const float* l = lds + base;

            float* o = outb + (size_t)(tyl + r * 8) * WW;
            #pragma unroll
            for (int c = 0; c < CC; ++c) {
                float v00 = l[c];
                float v01 = l[c + CSTR];
                float v10 = l[c + ROWSTR];
                float v11 = l[c + ROWSTR + CSTR];
                float v = v00 * w00 + v01 * w01 + v10 * w10 + v11 * w11;
                v = fminf(fmaxf(v, 0.0f), 1.0f);
                __builtin_nontemporal_store(v, o + (size_t)c * HW);
            }
            xs += dxs;
            ys += dys;
        }
    }
}

extern "C" void kernel_launch(void* const* d_in, const int* in_sizes, int n_in,
                              void* d_out, int out_size, void* d_ws, size_t ws_size,
                              hipStream_t stream) {
    const float* x      = (const float*)d_in[0];
    const float* angles = (const float*)d_in[1];
    const float* dx     = (const float*)d_in[2];
    const float* dy     = (const float*)d_in[3];
    float* out = (float*)d_out;

    GeometricAugment_kernel<<<NBLOCKS, 512, 0, stream>>>(x, angles, dx, dy, out);
}